// Round 13
// baseline (40.527 us; speedup 1.0000x reference)
//
#include <hip/hip_runtime.h>

#define IN_DIM 128
#define OUT_DIM 32
#define NHEAD 2
#define BINSZ 12500            // nodes per LDS bin (50 KB of u32) -> nbins=4
#define NSTRIPE 64             // edge stripes -> 256 edge blocks
#define THREADS 1024
#define PBLOCKS 256            // projection blocks co-launched with edge blocks
#define FIX 4.0f               // invsum fixed-point scale (inv*4)
// LDS u32 acc fields: count [26:31], selfdup [24:25], inv*4 [0:23]
// u16 partial fields: count [13:15] sat7, selfdup [11:12] sat3, inv*4 [0:10] sat2047
#define SELF_INV 1000000.0f    // r==c: d=0 -> fmax(d,1e-6) -> inv = 1e6 exactly

typedef float vfloat2 __attribute__((ext_vector_type(2)));
typedef float vfloat4 __attribute__((ext_vector_type(4)));
typedef int   vint4   __attribute__((ext_vector_type(4)));
typedef int   vint2   __attribute__((ext_vector_type(2)));
typedef unsigned short u16;

// ---- Kernel 1: heterogeneous: edge reduction + projection ----------------
__global__ __launch_bounds__(THREADS) void k_A(
        const int* __restrict__ row, const int* __restrict__ col,
        const float* __restrict__ pos, const float* __restrict__ x,
        const float* __restrict__ W,
        u16* __restrict__ partial, float2* __restrict__ S2,
        int N, int E, int nbins, int eblocks) {
    __shared__ __align__(16) unsigned acc[BINSZ];
    const int b = blockIdx.x;
    if (b < eblocks) {
        const int bin  = b % nbins;
        const int s    = b / nbins;
        const int base = bin * BINSZ;
        const int lim  = min(BINSZ, N - base);
        for (int j = threadIdx.x; j < BINSZ; j += THREADS) acc[j] = 0u;
        __syncthreads();

        const int slen = (E + NSTRIPE - 1) / NSTRIPE;
        const int e0 = s * slen;
        const int e1 = min(e0 + slen, E);

        auto accum = [&](int r, int c) {
            int rb = r - base;
            if ((unsigned)rb < (unsigned)lim) {
                unsigned add;
                if (r == c) {
                    add = (1u << 26) + (1u << 24);   // count + selfdup (inv = 1e6 exact, added in fold)
                } else {
                    float dx = pos[c * 3 + 0] - pos[r * 3 + 0];
                    float dy = pos[c * 3 + 1] - pos[r * 3 + 1];
                    float dz = pos[c * 3 + 2] - pos[r * 3 + 2];
                    float inv = 1.0f / fmaxf(sqrtf(dx * dx + dy * dy + dz * dz), 1e-6f);
                    add = (1u << 26) + (unsigned)(inv * FIX + 0.5f);
                }
                atomicAdd(&acc[rb], add);
            }
        };

        if (((e0 | e1) & 3) == 0) {          // int4 fast path (slen=12500 -> always)
            for (int e = e0 + (int)threadIdx.x * 4; e < e1; e += THREADS * 4) {
                vint4 r4 = __builtin_nontemporal_load((const vint4*)(row + e));
                vint4 c4 = __builtin_nontemporal_load((const vint4*)(col + e));
                accum(r4.x, c4.x); accum(r4.y, c4.y);
                accum(r4.z, c4.z); accum(r4.w, c4.w);
            }
        } else {
            for (int e = e0 + (int)threadIdx.x; e < e1; e += THREADS)
                accum(row[e], col[e]);
        }

        __syncthreads();
        // saturating u16 pack; every (s,node) slot written exactly once -> no pre-zero
        u16* dst = partial + (size_t)s * N + base;
        for (int j = threadIdx.x; j < lim; j += THREADS) {
            unsigned v    = acc[j];
            unsigned cnt  = min(v >> 26, 7u);
            unsigned self = min((v >> 24) & 3u, 3u);
            unsigned inv  = min(v & 0xFFFFFFu, 2047u);
            __builtin_nontemporal_store((u16)((cnt << 13) | (self << 11) | inv), dst + j);
        }
    } else {
        float* wl = (float*)acc;             // reuse LDS: wsum[h*128+j]
        if (threadIdx.x < NHEAD * IN_DIM) {
            const float4* wp = (const float4*)(W + threadIdx.x * OUT_DIM);
            float s = 0.f;
            #pragma unroll
            for (int q = 0; q < 8; ++q) {
                float4 v = wp[q];
                s += (v.x + v.y) + (v.z + v.w);
            }
            wl[threadIdx.x] = s;
        }
        __syncthreads();

        const int lid = threadIdx.x & 15;
        const float4* wv = (const float4*)wl;
        float4 w0a = wv[lid * 2],      w0b = wv[lid * 2 + 1];
        float4 w1a = wv[32 + lid * 2], w1b = wv[32 + lid * 2 + 1];

        const int g      = (b - eblocks) * (THREADS / 16) + (threadIdx.x >> 4);
        const int stride = (gridDim.x - eblocks) * (THREADS / 16);
        for (int i = g; i < N; i += stride) {
            const vfloat4* xp = (const vfloat4*)(x + (size_t)i * IN_DIM);
            vfloat4 xa = __builtin_nontemporal_load(xp + lid * 2);
            vfloat4 xb = __builtin_nontemporal_load(xp + lid * 2 + 1);
            float s0 = (xa.x * w0a.x + xa.y * w0a.y + xa.z * w0a.z + xa.w * w0a.w)
                     + (xb.x * w0b.x + xb.y * w0b.y + xb.z * w0b.z + xb.w * w0b.w);
            float s1 = (xa.x * w1a.x + xa.y * w1a.y + xa.z * w1a.z + xa.w * w1a.w)
                     + (xb.x * w1b.x + xb.y * w1b.y + xb.z * w1b.z + xb.w * w1b.w);
            #pragma unroll
            for (int off = 8; off >= 1; off >>= 1) {
                s0 += __shfl_xor(s0, off, 16);
                s1 += __shfl_xor(s1, off, 16);
            }
            if (lid == 0) S2[i] = make_float2(s0, s1);
        }
    }
}

// ---- Kernel 2: fold 64 stripes -> node2[i] = S2[i]*2*(1+invsum)/(1+deg) ---
// Tile of 64 nodes per block-iter; wave g reads stripes [4g,4g+4) (64
// consecutive u16 per load, coalesced 128B), LDS 16->1 reduce.
__global__ __launch_bounds__(THREADS) void k_B(
        const u16* __restrict__ partial, const float2* __restrict__ S2,
        float2* __restrict__ node2, int N) {
    __shared__ unsigned sh_i[16 * 64], sh_cs[16 * 64];
    const int il = threadIdx.x & 63;
    const int g  = threadIdx.x >> 6;     // wave id 0..15
    const int ntiles = (N + 63) / 64;
    for (int tile = blockIdx.x; tile < ntiles; tile += gridDim.x) {
        const int i = tile * 64 + il;
        unsigned isum = 0, csum = 0, ssum = 0;
        if (i < N) {
            #pragma unroll
            for (int q = 0; q < 4; ++q) {
                unsigned v = __builtin_nontemporal_load(
                    partial + (size_t)(g * 4 + q) * N + i);
                isum += v & 0x7FFu;
                ssum += (v >> 11) & 3u;
                csum += v >> 13;
            }
        }
        sh_i[g * 64 + il]  = isum;
        sh_cs[g * 64 + il] = (csum << 8) | ssum;   // csum<=28 (5b)<<8 | ssum<=12
        __syncthreads();
        if (g == 0 && i < N) {
            unsigned ti = 0, tcs = 0;
            #pragma unroll
            for (int q = 0; q < 16; ++q) {
                ti  += sh_i[q * 64 + il];
                tcs += sh_cs[q * 64 + il];
            }
            unsigned tc = tcs >> 8;          // total count (<=448, fits)
            unsigned ts = tcs & 0xFFu;       // total selfdups
            float invsum = (float)ti * (1.0f / FIX) + SELF_INV * (float)ts;
            float fac = 2.0f * (1.0f + invsum) / (1.0f + (float)tc);
            float2 sv = S2[i];
            node2[i] = make_float2(sv.x * fac, sv.y * fac);
        }
        __syncthreads();
    }
}

// ---- Kernel 3: out[h*M+k] = node2[row2[k]].h - node2[col2[k]].h -----------
// 2 edges/thread; self-loop tail (k >= E) exactly 0. NT row/col loads and NT
// out stores keep L2 free for the node2 gathers (32x reuse).
__global__ __launch_bounds__(THREADS) void k_C(
        const int* __restrict__ row, const int* __restrict__ col,
        const float2* __restrict__ node2, float* __restrict__ out,
        int E, int M) {
    const bool mEven = ((M & 1) == 0);
    const int k = (blockIdx.x * THREADS + (int)threadIdx.x) * 2;
    if (k >= M) return;
    float o0a = 0.f, o1a = 0.f, o0b = 0.f, o1b = 0.f;
    const bool pair = (k + 1 < M);
    if (k + 1 < E) {
        vint2 r2 = __builtin_nontemporal_load((const vint2*)(row + k));
        vint2 c2 = __builtin_nontemporal_load((const vint2*)(col + k));
        float2 nr0 = node2[r2.x], nc0 = node2[c2.x];
        float2 nr1 = node2[r2.y], nc1 = node2[c2.y];
        o0a = nr0.x - nc0.x; o1a = nr0.y - nc0.y;
        o0b = nr1.x - nc1.x; o1b = nr1.y - nc1.y;
    } else if (k < E) {
        float2 nr = node2[row[k]], nc = node2[col[k]];
        o0a = nr.x - nc.x; o1a = nr.y - nc.y;
    }
    if (pair && mEven) {
        vfloat2 a; a.x = o0a; a.y = o0b;
        vfloat2 c; c.x = o1a; c.y = o1b;
        __builtin_nontemporal_store(a, (vfloat2*)(out + k));
        __builtin_nontemporal_store(c, (vfloat2*)(out + M + k));
    } else {
        out[k] = o0a;         out[M + k] = o1a;
        if (pair) { out[k + 1] = o0b; out[M + k + 1] = o1b; }
    }
}

extern "C" void kernel_launch(void* const* d_in, const int* in_sizes, int n_in,
                              void* d_out, int out_size, void* d_ws, size_t ws_size,
                              hipStream_t stream) {
    const float* x   = (const float*)d_in[0];
    const float* pos = (const float*)d_in[1];
    const float* W   = (const float*)d_in[2];
    // d_in[3] (attn) unused: per-segment logits are identical -> softmax = 1/count.
    const int* row = (const int*)d_in[4];
    const int* col = (const int*)d_in[5];
    float* out = (float*)d_out;

    const int N = in_sizes[0] / IN_DIM;
    const int E = in_sizes[4];
    const int M = E + N;
    const int nbins = (N + BINSZ - 1) / BINSZ;     // 4 for N=50000
    const int eblocks = nbins * NSTRIPE;           // 256

    float2* S2    = (float2*)d_ws;                 // N float2
    float2* node2 = S2 + N;                        // N float2
    u16* partial  = (u16*)(node2 + N);             // NSTRIPE * N u16 (6.4 MB)

    k_A<<<eblocks + PBLOCKS, THREADS, 0, stream>>>(row, col, pos, x, W,
                                                   partial, S2, N, E, nbins, eblocks);
    k_B<<<(N + 63) / 64, THREADS, 0, stream>>>(partial, S2, node2, N);
    k_C<<<(M / 2 + THREADS - 1) / THREADS, THREADS, 0, stream>>>(row, col, node2,
                                                                 out, E, M);
}

// Round 14
// 36.987 us; speedup vs baseline: 1.0957x; 1.0957x over previous
//
#include <hip/hip_runtime.h>

#define IN_DIM 128
#define OUT_DIM 32
#define NHEAD 2
#define BINSZ 12500            // nodes per LDS bin (50 KB of u32) -> nbins=4
#define NSTRIPE 64             // edge stripes -> 256 edge blocks
#define THREADS 1024
#define PBLOCKS 256            // projection blocks co-launched with edge blocks
#define FIX 16.0f              // invsum fixed-point scale
#define CSHIFT 26              // u32: count [26:31], invsum*16 [0:25]
#define IMASK ((1u << CSHIFT) - 1u)

typedef float vfloat2 __attribute__((ext_vector_type(2)));   // native vec for nontemporal builtin

// ---- Kernel 1: heterogeneous: edge reduction + projection ----------------
// Edge block (bin, s): scan stripe s (int4 coalesced), LDS-accumulate in-bin
// edges (u32: count<<26 + round(inv*16); a r==c dup contributes 1.6e7 << 2^26,
// per-(bin,stripe) fields can't overflow), nontemporal-store bin slice to
// partial[s][binrange] (exactly-once -> no pre-zero).
// Proj block: S2[i] = {dot(x_i,wsum0), dot(x_i,wsum1)}, 16 lanes per node.
__global__ __launch_bounds__(THREADS) void k_A(
        const int* __restrict__ row, const int* __restrict__ col,
        const float* __restrict__ pos, const float* __restrict__ x,
        const float* __restrict__ W,
        unsigned* __restrict__ partial, float2* __restrict__ S2,
        int N, int E, int nbins, int eblocks) {
    __shared__ __align__(16) unsigned acc[BINSZ];
    const int b = blockIdx.x;
    if (b < eblocks) {
        const int bin  = b % nbins;
        const int s    = b / nbins;
        const int base = bin * BINSZ;
        const int lim  = min(BINSZ, N - base);
        for (int j = threadIdx.x; j < BINSZ; j += THREADS) acc[j] = 0u;
        __syncthreads();

        const int slen = (E + NSTRIPE - 1) / NSTRIPE;
        const int e0 = s * slen;
        const int e1 = min(e0 + slen, E);

        auto accum = [&](int r, int c) {
            int rb = r - base;
            if ((unsigned)rb < (unsigned)lim) {
                float dx = pos[c * 3 + 0] - pos[r * 3 + 0];
                float dy = pos[c * 3 + 1] - pos[r * 3 + 1];
                float dz = pos[c * 3 + 2] - pos[r * 3 + 2];
                float inv = 1.0f / fmaxf(sqrtf(dx * dx + dy * dy + dz * dz), 1e-6f);
                atomicAdd(&acc[rb], (1u << CSHIFT) + (unsigned)(inv * FIX + 0.5f));
            }
        };

        if (((e0 | e1) & 3) == 0) {          // int4 fast path (slen=12500 -> always)
            for (int e = e0 + (int)threadIdx.x * 4; e < e1; e += THREADS * 4) {
                int4 r4 = *(const int4*)(row + e);
                int4 c4 = *(const int4*)(col + e);
                accum(r4.x, c4.x); accum(r4.y, c4.y);
                accum(r4.z, c4.z); accum(r4.w, c4.w);
            }
        } else {
            for (int e = e0 + (int)threadIdx.x; e < e1; e += THREADS)
                accum(row[e], col[e]);
        }

        __syncthreads();
        unsigned* dst = partial + (size_t)s * N + base;
        for (int j = threadIdx.x; j < lim; j += THREADS)
            __builtin_nontemporal_store(acc[j], dst + j);   // write-once, read next kernel
    } else {
        float* wl = (float*)acc;             // reuse LDS: wsum[h*128+j]
        if (threadIdx.x < NHEAD * IN_DIM) {
            const float4* wp = (const float4*)(W + threadIdx.x * OUT_DIM);
            float s = 0.f;
            #pragma unroll
            for (int q = 0; q < 8; ++q) {
                float4 v = wp[q];
                s += (v.x + v.y) + (v.z + v.w);
            }
            wl[threadIdx.x] = s;
        }
        __syncthreads();

        const int lid = threadIdx.x & 15;
        const float4* wv = (const float4*)wl;
        float4 w0a = wv[lid * 2],      w0b = wv[lid * 2 + 1];
        float4 w1a = wv[32 + lid * 2], w1b = wv[32 + lid * 2 + 1];

        const int g      = (b - eblocks) * (THREADS / 16) + (threadIdx.x >> 4);
        const int stride = (gridDim.x - eblocks) * (THREADS / 16);
        for (int i = g; i < N; i += stride) {
            const float4* xp = (const float4*)(x + (size_t)i * IN_DIM);
            float4 xa = xp[lid * 2], xb = xp[lid * 2 + 1];
            float s0 = (xa.x * w0a.x + xa.y * w0a.y + xa.z * w0a.z + xa.w * w0a.w)
                     + (xb.x * w0b.x + xb.y * w0b.y + xb.z * w0b.z + xb.w * w0b.w);
            float s1 = (xa.x * w1a.x + xa.y * w1a.y + xa.z * w1a.z + xa.w * w1a.w)
                     + (xb.x * w1b.x + xb.y * w1b.y + xb.z * w1b.z + xb.w * w1b.w);
            #pragma unroll
            for (int off = 8; off >= 1; off >>= 1) {
                s0 += __shfl_xor(s0, off, 16);
                s1 += __shfl_xor(s1, off, 16);
            }
            if (lid == 0) S2[i] = make_float2(s0, s1);
        }
    }
}

// ---- Kernel 2: fold 64 stripes -> node2[i] = S2[i]*2*(1+invsum)/(1+deg) ---
// Tile of 64 nodes per block-iter; wave g reads stripes [4g,4g+4) (64
// consecutive u32 per load, fully coalesced), LDS 16->1 reduce.
__global__ __launch_bounds__(THREADS) void k_B(
        const unsigned* __restrict__ partial, const float2* __restrict__ S2,
        float2* __restrict__ node2, int N) {
    __shared__ unsigned sh_i[16 * 64], sh_c[16 * 64];
    const int il = threadIdx.x & 63;
    const int g  = threadIdx.x >> 6;     // wave id 0..15
    const int ntiles = (N + 63) / 64;
    for (int tile = blockIdx.x; tile < ntiles; tile += gridDim.x) {
        const int i = tile * 64 + il;
        unsigned isum = 0, csum = 0;
        if (i < N) {
            #pragma unroll
            for (int q = 0; q < NSTRIPE / 16; ++q) {
                unsigned v = partial[(size_t)(g * (NSTRIPE / 16) + q) * N + i];
                isum += v & IMASK;
                csum += v >> CSHIFT;
            }
        }
        sh_i[g * 64 + il] = isum;
        sh_c[g * 64 + il] = csum;
        __syncthreads();
        if (g == 0 && i < N) {
            unsigned ti = 0, tc = 0;
            #pragma unroll
            for (int q = 0; q < 16; ++q) {
                ti += sh_i[q * 64 + il];
                tc += sh_c[q * 64 + il];
            }
            float invsum = (float)ti * (1.0f / FIX);
            float fac = 2.0f * (1.0f + invsum) / (1.0f + (float)tc);
            float2 sv = S2[i];
            node2[i] = make_float2(sv.x * fac, sv.y * fac);
        }
        __syncthreads();
    }
}

// ---- Kernel 3: out[h*M+k] = node2[row2[k]].h - node2[col2[k]].h -----------
// 2 edges/thread; self-loop tail (k >= E) exactly 0. Nontemporal out stores
// keep L2 free for the node2 gathers.
__global__ __launch_bounds__(THREADS) void k_C(
        const int* __restrict__ row, const int* __restrict__ col,
        const float2* __restrict__ node2, float* __restrict__ out,
        int E, int M) {
    const bool mEven = ((M & 1) == 0);
    const int k = (blockIdx.x * THREADS + (int)threadIdx.x) * 2;
    if (k >= M) return;
    float o0a = 0.f, o1a = 0.f, o0b = 0.f, o1b = 0.f;
    const bool pair = (k + 1 < M);
    if (k < E) {
        float2 nr = node2[row[k]], nc = node2[col[k]];
        o0a = nr.x - nc.x; o1a = nr.y - nc.y;
    }
    if (pair && k + 1 < E) {
        float2 nr = node2[row[k + 1]], nc = node2[col[k + 1]];
        o0b = nr.x - nc.x; o1b = nr.y - nc.y;
    }
    if (pair && mEven) {
        vfloat2 a; a.x = o0a; a.y = o0b;
        vfloat2 c; c.x = o1a; c.y = o1b;
        __builtin_nontemporal_store(a, (vfloat2*)(out + k));
        __builtin_nontemporal_store(c, (vfloat2*)(out + M + k));
    } else {
        out[k] = o0a;         out[M + k] = o1a;
        if (pair) { out[k + 1] = o0b; out[M + k + 1] = o1b; }
    }
}

extern "C" void kernel_launch(void* const* d_in, const int* in_sizes, int n_in,
                              void* d_out, int out_size, void* d_ws, size_t ws_size,
                              hipStream_t stream) {
    const float* x   = (const float*)d_in[0];
    const float* pos = (const float*)d_in[1];
    const float* W   = (const float*)d_in[2];
    // d_in[3] (attn) unused: per-segment logits are identical -> softmax = 1/count.
    const int* row = (const int*)d_in[4];
    const int* col = (const int*)d_in[5];
    float* out = (float*)d_out;

    const int N = in_sizes[0] / IN_DIM;
    const int E = in_sizes[4];
    const int M = E + N;
    const int nbins = (N + BINSZ - 1) / BINSZ;     // 4 for N=50000
    const int eblocks = nbins * NSTRIPE;           // 256

    float2* S2    = (float2*)d_ws;                 // N float2
    float2* node2 = S2 + N;                        // N float2
    unsigned* partial = (unsigned*)(node2 + N);    // NSTRIPE * N u32 (12.8 MB)

    k_A<<<eblocks + PBLOCKS, THREADS, 0, stream>>>(row, col, pos, x, W,
                                                   partial, S2, N, E, nbins, eblocks);
    k_B<<<(N + 63) / 64, THREADS, 0, stream>>>(partial, S2, node2, N);
    k_C<<<(M / 2 + THREADS - 1) / THREADS, THREADS, 0, stream>>>(row, col, node2,
                                                                 out, E, M);
}